// Round 16
// baseline (1091.908 us; speedup 1.0000x reference)
//
#include <hip/hip_runtime.h>
#include <hip/hip_bf16.h>
#include <cstdint>
#include <cstddef>

#define VOCAB 32000
#define HIDDEN 1024
#define BATCH 32
#define SEQ 128

typedef __attribute__((ext_vector_type(8))) short short8v;
typedef __attribute__((ext_vector_type(4))) float float4v;
typedef __attribute__((ext_vector_type(2))) unsigned int uint2v;

__device__ __forceinline__ unsigned short f2bf(float f) {
    unsigned int x = __float_as_uint(f);
    unsigned int r = x + 0x7fffu + ((x >> 16) & 1u);  // RNE
    return (unsigned short)(r >> 16);
}

// ---------------- small prep: 3 HxH transpose-converts + state init (one launch) ----------------
__global__ __launch_bounds__(256) void k_prep(const float* __restrict__ whr, unsigned short* __restrict__ wrt,
                                              const float* __restrict__ whz, unsigned short* __restrict__ wzt,
                                              const float* __restrict__ whh, unsigned short* __restrict__ wht,
                                              const float* __restrict__ state, unsigned short* __restrict__ hinit) {
    const int b = blockIdx.x;
    const int t = threadIdx.x;
    if (b >= 768) {
        int i = (b - 768) * 256 + t;
        if (i < BATCH * HIDDEN) hinit[i] = f2bf(state[i]);
        return;
    }
    __shared__ float tile[64][65];
    const float* in    = (b < 256) ? whr : (b < 512) ? whz : whh;
    unsigned short* op = (b < 256) ? wrt : (b < 512) ? wzt : wht;
    const int q  = b & 255;
    const int jb = q & 15, kb = q >> 4;
    const int c  = t & 63;
    const int r0 = (t >> 6) * 16;
#pragma unroll
    for (int i = 0; i < 16; i++) {
        int r = r0 + i;
        tile[r][c] = in[(size_t)(kb * 64 + r) * HIDDEN + jb * 64 + c];
    }
    __syncthreads();
#pragma unroll
    for (int i = 0; i < 16; i++) {
        int r = r0 + i;
        op[(size_t)(jb * 64 + r) * HIDDEN + kb * 64 + c] = f2bf(tile[c][r]);
    }
}

// ---------------- persistent recurrence kernel + co-resident bt-transpose ----------------
// (r14-proven structure; only change this round: 4-deep pipelined poll.)

#define WAIT_VM0 asm volatile("s_waitcnt vmcnt(0)" ::: "memory")
#define LGKM0    asm volatile("s_waitcnt lgkmcnt(0)" ::: "memory")

#define ST8_WT(P, V) \
    asm volatile("global_store_dwordx2 %0, %1, off sc0 sc1" ::"v"(P), "v"(V) : "memory")

// 4-deep pipelined poll: four flag loads in rotation -> each check waits only
// vmcnt(3), sampling period ~RTT/4 (r13 proved the sampling-period mechanism).
// Watchdog-capped: protocol failure = wrong absmax, never a hang.
__device__ __forceinline__ void row_poll(const unsigned int* row, unsigned int tag) {
    const unsigned int* p = row + (threadIdx.x & 63);
    unsigned int a = __hip_atomic_load(p, __ATOMIC_RELAXED, __HIP_MEMORY_SCOPE_AGENT);
    unsigned int b = __hip_atomic_load(p, __ATOMIC_RELAXED, __HIP_MEMORY_SCOPE_AGENT);
    unsigned int c = __hip_atomic_load(p, __ATOMIC_RELAXED, __HIP_MEMORY_SCOPE_AGENT);
    int guard = 0;
    while (true) {
        unsigned int d = __hip_atomic_load(p, __ATOMIC_RELAXED, __HIP_MEMORY_SCOPE_AGENT);
        if (__all((int)(a >= tag))) break;
        a = __hip_atomic_load(p, __ATOMIC_RELAXED, __HIP_MEMORY_SCOPE_AGENT);
        if (__all((int)(b >= tag))) break;
        b = __hip_atomic_load(p, __ATOMIC_RELAXED, __HIP_MEMORY_SCOPE_AGENT);
        if (__all((int)(c >= tag))) break;
        c = __hip_atomic_load(p, __ATOMIC_RELAXED, __HIP_MEMORY_SCOPE_AGENT);
        if (__all((int)(d >= tag))) break;
        if (++guard > 8192) break;
    }
}

__global__ __launch_bounds__(256, 1) void k_rnn(const int* __restrict__ x,
                                                const float* __restrict__ state,
                                                const unsigned short* __restrict__ wrt,
                                                const unsigned short* __restrict__ wzt,
                                                const unsigned short* __restrict__ wht,
                                                const float* __restrict__ W_xr, const float* __restrict__ b_r,
                                                const float* __restrict__ W_xz, const float* __restrict__ b_z,
                                                const float* __restrict__ W_xh, const float* __restrict__ b_h,
                                                const unsigned short* __restrict__ hinit, // [32][1024]
                                                unsigned short* __restrict__ hall,        // [128][32][1024]
                                                unsigned short* __restrict__ rhall,       // [128][32][1024]
                                                float* __restrict__ hstate_out,           // [32][1024]
                                                unsigned int* __restrict__ mbox,          // [2][64][64]
                                                const float* __restrict__ who,            // [1024][32000]
                                                unsigned short* __restrict__ bt) {        // [32000][1024]
    const int bid = blockIdx.x;

    __shared__ short8v wlds[3][32][64];      // 96 KB: [mat][k-subtile][lane]
    __shared__ int xs[16 * SEQ];             // 8 KB: own group's tokens
    __shared__ unsigned short pack[16 * 16]; // 512 B exchange tile

    if (bid >= 128) {
        // ---------- bt-transpose role (LDS-free, all 4 waves) ----------
        const int n = (bid - 128) * 64 + (threadIdx.x & 63);
        const int w4 = threadIdx.x >> 6;
        for (int k0 = w4 * 256; k0 < w4 * 256 + 256; k0 += 8) {
            short8v v;
#pragma unroll
            for (int e = 0; e < 8; e++)
                v[e] = (short)f2bf(who[(size_t)(k0 + e) * VOCAB + n]);
            *(short8v*)&bt[(size_t)n * HIDDEN + k0] = v;
        }
        return;
    }
    if (threadIdx.x >= 64) return;  // workers: wave 0 only (r10-proven pattern)

    const int g   = bid >> 6;
    const int jsl = bid & 63;
    const int j0  = jsl * 16;
    const int b0  = g * 16;
    const int l   = threadIdx.x;  // 0..63
    const int llo = l & 15;
    const int lhi = l >> 4;
    const int jg  = j0 + llo;

    unsigned int* gm           = mbox + g * 64 * 64;  // this group's mailbox block
    const unsigned int* myrow  = gm + jsl * 64;       // my private row (poll target)
    unsigned int* pushtgt      = gm + l * 64 + jsl;   // lane l pushes to consumer l

    // ---- one-time: weights -> LDS (B-frags), tokens -> LDS ----
#pragma unroll
    for (int i = 0; i < 32; i++) {
        const size_t off = (size_t)jg * HIDDEN + i * 32 + lhi * 8;
        wlds[0][i][l] = *(const short8v*)&wrt[off];
        wlds[1][i][l] = *(const short8v*)&wzt[off];
        wlds[2][i][l] = *(const short8v*)&wht[off];
    }
    for (int i = l; i < 16 * SEQ; i += 64)
        xs[i] = x[(size_t)(b0 + (i >> 7)) * SEQ + (i & 127)];

    const float brv = b_r[jg], bzv = b_z[jg], bhv = b_h[jg];
    float4v hO;
#pragma unroll
    for (int q = 0; q < 4; q++) hO[q] = state[(b0 + 4 * lhi + q) * HIDDEN + jg];
    LGKM0;  // LDS preload visible to own wave's reads

    for (int t = 0; t < SEQ; t++) {
        const unsigned short* hprev =
            t ? (hall + (size_t)(t - 1) * BATCH * HIDDEN) : hinit;
        unsigned short* rhp = rhall + (size_t)t * BATCH * HIDDEN;
        unsigned short* hp  = hall + (size_t)t * BATCH * HIDDEN;

        // embedding gathers issued BEFORE the poll (latency hides under it)
        int tok[4];
#pragma unroll
        for (int q = 0; q < 4; q++) tok[q] = xs[(4 * lhi + q) * SEQ + t];
        float xr[4], xz[4], xh[4];
#pragma unroll
        for (int q = 0; q < 4; q++) {
            xr[q] = W_xr[(size_t)tok[q] * HIDDEN + jg];
            xz[q] = W_xz[(size_t)tok[q] * HIDDEN + jg];
            xh[q] = W_xh[(size_t)tok[q] * HIDDEN + jg];
        }

        // ---- Phase A: wait h(t-1) via private row, compute r,z ----
        if (t) row_poll(myrow, 2u * (unsigned)t);

        short8v af[32];
#pragma unroll
        for (int i = 0; i < 32; i++)
            af[i] = *(const short8v*)&hprev[(b0 + llo) * HIDDEN + i * 32 + lhi * 8];

        float4v aR0 = {0.f, 0.f, 0.f, 0.f}, aR1 = {0.f, 0.f, 0.f, 0.f};
        float4v aZ0 = {0.f, 0.f, 0.f, 0.f}, aZ1 = {0.f, 0.f, 0.f, 0.f};
#pragma unroll
        for (int i = 0; i < 32; i += 2) {
            aR0 = __builtin_amdgcn_mfma_f32_16x16x32_bf16(af[i],     wlds[0][i][l],     aR0, 0, 0, 0);
            aZ0 = __builtin_amdgcn_mfma_f32_16x16x32_bf16(af[i],     wlds[1][i][l],     aZ0, 0, 0, 0);
            aR1 = __builtin_amdgcn_mfma_f32_16x16x32_bf16(af[i + 1], wlds[0][i + 1][l], aR1, 0, 0, 0);
            aZ1 = __builtin_amdgcn_mfma_f32_16x16x32_bf16(af[i + 1], wlds[1][i + 1][l], aZ1, 0, 0, 0);
        }

        float4v zv;
#pragma unroll
        for (int q = 0; q < 4; q++) {
            float sr = aR0[q] + aR1[q] + xr[q] + brv;
            float sz = aZ0[q] + aZ1[q] + xz[q] + bzv;
            float rv = 1.f / (1.f + __expf(-sr));
            zv[q]    = 1.f / (1.f + __expf(-sz));
            pack[(4 * lhi + q) * 16 + llo] = f2bf(rv * hO[q]);
        }
        LGKM0;
        __builtin_amdgcn_wave_barrier();
        {   // publish rh tile: 64x8B WT stores, drain, then push tag to all consumers
            uint2v v = *(const uint2v*)&pack[(l >> 2) * 16 + (l & 3) * 4];
            ST8_WT(&rhp[(b0 + (l >> 2)) * HIDDEN + j0 + (l & 3) * 4], v);
            WAIT_VM0;
            __hip_atomic_store(pushtgt, 2u * (unsigned)t + 1u, __ATOMIC_RELAXED,
                               __HIP_MEMORY_SCOPE_AGENT);
        }

        // ---- Phase B: wait rh via private row, compute candidate + update ----
        row_poll(myrow, 2u * (unsigned)t + 1u);

        short8v ar[32];
#pragma unroll
        for (int i = 0; i < 32; i++)
            ar[i] = *(const short8v*)&rhp[(b0 + llo) * HIDDEN + i * 32 + lhi * 8];

        float4v aC0 = {0.f, 0.f, 0.f, 0.f}, aC1 = {0.f, 0.f, 0.f, 0.f};
#pragma unroll
        for (int i = 0; i < 32; i += 2) {
            aC0 = __builtin_amdgcn_mfma_f32_16x16x32_bf16(ar[i],     wlds[2][i][l],     aC0, 0, 0, 0);
            aC1 = __builtin_amdgcn_mfma_f32_16x16x32_bf16(ar[i + 1], wlds[2][i + 1][l], aC1, 0, 0, 0);
        }
#pragma unroll
        for (int q = 0; q < 4; q++) {
            float a = aC0[q] + aC1[q] + xh[q] + bhv;
            a = fminf(15.f, fmaxf(-15.f, a));
            float e2   = __expf(2.f * a);
            float cand = (e2 - 1.f) / (e2 + 1.f);
            float hn   = zv[q] * hO[q] + (1.f - zv[q]) * cand;
            hO[q]      = hn;
            pack[(4 * lhi + q) * 16 + llo] = f2bf(hn);
        }
        LGKM0;
        __builtin_amdgcn_wave_barrier();
        {   // publish h tile into hall[t] (also the GEMM A matrix)
            uint2v v = *(const uint2v*)&pack[(l >> 2) * 16 + (l & 3) * 4];
            ST8_WT(&hp[(b0 + (l >> 2)) * HIDDEN + j0 + (l & 3) * 4], v);
            WAIT_VM0;
            __hip_atomic_store(pushtgt, 2u * (unsigned)t + 2u, __ATOMIC_RELAXED,
                               __HIP_MEMORY_SCOPE_AGENT);
        }
    }

#pragma unroll
    for (int q = 0; q < 4; q++)
        hstate_out[(b0 + 4 * lhi + q) * HIDDEN + jg] = hO[q];
}

// ---------------- 256x256 8-phase output-projection GEMM (r12-proven) ----------------
#define GTM 16   // M tiles
#define GTN 125  // N tiles

__device__ __forceinline__ void gload_lds16(const void* g, void* l) {
    __builtin_amdgcn_global_load_lds((const __attribute__((address_space(1))) void*)g,
                                     (__attribute__((address_space(3))) void*)l, 16, 0, 0);
}

__device__ __forceinline__ void stage_half(const unsigned short* __restrict__ mbase,
                                           unsigned short* ldsm, int half, int isB,
                                           int kt, int tid) {
#pragma unroll
    for (int i = 0; i < 2; i++) {
        int s  = i * 512 + tid;
        int ri = s >> 3;
        int cb = (s & 7) * 16;  // byte col in [0,128)
        int rt = isB ? ((ri >> 5) * 64 + half * 32 + (ri & 31))
                     : ((ri >> 6) * 128 + half * 64 + (ri & 63));
        int cbs = cb ^ ((rt & 7) << 4);  // swizzled source col (bytes)
        gload_lds16(mbase + (size_t)rt * HIDDEN + kt * 64 + (cbs >> 1),
                    ldsm + rt * 64 + (cb >> 1));
    }
}

__global__ __launch_bounds__(512, 2) void k_gemm8(const unsigned short* __restrict__ A,
                                                  const unsigned short* __restrict__ B,
                                                  const float* __restrict__ bo,
                                                  float* __restrict__ out) {
    __shared__ unsigned short lds[2][2][256 * 64];  // 128 KB: [dbuf][A/B][row*64+col]

    const int wg   = blockIdx.x;                 // 0..1999 (2000 % 8 == 0)
    const int swz  = (wg & 7) * 250 + (wg >> 3); // XCD-aware bijective swizzle
    const int mb   = swz / GTN;
    const int nb   = swz % GTN;
    const int row0 = mb * 256, col0 = nb * 256;

    const int tid = threadIdx.x;
    const int w   = tid >> 6;
    const int wm  = w >> 2;   // 0..1
    const int wn  = w & 3;    // 0..3
    const int l   = tid & 63;
    const int llo = l & 15;
    const int lhi = l >> 4;

    const unsigned short* Ab = A + (size_t)row0 * HIDDEN;
    const unsigned short* Bb = B + (size_t)col0 * HIDDEN;

    float4v acc[8][4];
#pragma unroll
    for (int i = 0; i < 8; i++)
#pragma unroll
        for (int j = 0; j < 4; j++) acc[i][j] = float4v{0.f, 0.f, 0.f, 0.f};

    // ---- prologue: kt0 all 4 halves, kt1 first 2 halves; retire kt0 ----
    stage_half(Ab, &lds[0][0][0], 0, 0, 0, tid);
    stage_half(Bb, &lds[0][1][0], 0, 1, 0, tid);
    stage_half(Ab, &lds[0][0][0], 1, 0, 0, tid);
    stage_half(Bb, &lds[0][1][0], 1, 1, 0, tid);
    stage_half(Ab, &lds[1][0][0], 0, 0, 1, tid);
    stage_half(Bb, &lds[1][1][0], 0, 1, 1, tid);
    asm volatile("s_waitcnt vmcnt(4)" ::: "memory");
    __builtin_amdgcn_s_barrier();

    for (int kt = 0; kt < 16; kt++) {
        unsigned short* lA = &lds[kt & 1][0][0];
        unsigned short* lB = &lds[kt & 1][1][0];
        unsigned short* nA = &lds[(kt & 1) ^ 1][0][0];
        unsigned short* nB = &lds[(kt & 1) ^ 1][1][0];
        short8v afr[4][2];
        short8v bfr[2][2][2];

        // ---------- phase 1: quad(mh0, nh0); stage kt+1 A-mh1 ----------
#pragma unroll
        for (int mfq = 0; mfq < 4; mfq++)
#pragma unroll
            for (int ks = 0; ks < 2; ks++) {
                int rt = wm * 128 + mfq * 16 + llo;
                int cb = ks * 64 + lhi * 16;
                afr[mfq][ks] = *(const short8v*)&lA[rt * 64 + ((cb ^ ((rt & 7) << 4)) >> 1)];
            }
#pragma unroll
        for (int nfq = 0; nfq < 2; nfq++)
#pragma unroll
            for (int ks = 0; ks < 2; ks++) {
                int rt = wn * 64 + nfq * 16 + llo;
                int cb = ks * 64 + lhi * 16;
                bfr[0][nfq][ks] = *(const short8v*)&lB[rt * 64 + ((cb ^ ((rt & 7) << 4)) >> 1)];
            }
        if (kt + 1 < 16) stage_half(Ab, nA, 1, 0, kt + 1, tid);
        __builtin_amdgcn_s_barrier();
        __builtin_amdgcn_s_setprio(1);
#pragma unroll
        for (int mfq = 0; mfq < 4; mfq++)
#pragma unroll
            for (int nfq = 0; nfq < 2; nfq++)
#pragma unroll
                for (int ks = 0; ks < 2; ks++)
                    acc[mfq][nfq] = __builtin_amdgcn_mfma_f32_16x16x32_bf16(
                        afr[mfq][ks], bfr[0][nfq][ks], acc[mfq][nfq], 0, 0, 0);
        __builtin_amdgcn_s_setprio(0);
        __builtin_amdgcn_s_barrier();

        // ---------- phase 2: quad(mh0, nh1); stage kt+1 B-nh1 ----------
#pragma unroll
        for (int nfq = 0; nfq < 2; nfq++)
#pragma unroll
            for (int ks = 0; ks < 2; ks++) {
                int rt = wn * 64 + 32 + nfq * 16 + llo;
                int cb = ks * 64 + lhi * 16;
                bfr[1][nfq][ks] = *(const short8v*)&lB[rt * 64 + ((cb ^ ((rt & 7) << 4)) >> 1)];
            }
        if (kt + 1 < 16) stage_half(Bb, nB, 1, 1, kt + 1, tid);
        __builtin_amdgcn_s_barrier();
        __builtin_amdgcn_s_setprio(1);
#pragma unroll
        for (int mfq = 0; mfq < 4; mfq++)
#pragma unroll
            for (int nfq = 0; nfq < 2; nfq++)
#pragma unroll
                for (int ks = 0; ks < 2; ks++)
                    acc[mfq][2 + nfq] = __builtin_amdgcn_mfma_f32_16x16x32_bf16(
                        afr[mfq][ks], bfr[1][nfq][ks], acc[mfq][2 + nfq], 0, 0, 0);
        __builtin_amdgcn_s_setprio(0);
        __builtin_amdgcn_s_barrier();

        // ---------- phase 3: quad(mh1, nh0); stage kt+2 A-mh0 (region freed @p2) ----------
#pragma unroll
        for (int mfq = 0; mfq < 4; mfq++)
#pragma unroll
            for (int ks = 0; ks < 2; ks++) {
                int rt = wm * 128 + 64 + mfq * 16 + llo;
                int cb = ks * 64 + lhi * 16;
                afr[mfq][ks] = *(const short8v*)&lA[rt * 64 + ((cb ^ ((rt & 7) << 4)) >> 1)];
            }
        if (kt + 2 < 16) stage_half(Ab, lA, 0, 0, kt + 2, tid);
        __builtin_amdgcn_s_barrier();
        __builtin_amdgcn_s_setprio(1);
#pragma unroll
        for (int mfq = 0; mfq < 4; mfq++)
#pragma unroll
            for (int nfq = 0; nfq < 2; nfq++)
#pragma unroll
                for (int ks = 0; ks < 2; ks++)
                    acc[4 + mfq][nfq] = __builtin_amdgcn_mfma_f32_16x16x32_bf16(
                        afr[mfq][ks], bfr[0][nfq][ks], acc[4 + mfq][nfq], 0, 0, 0);
        __builtin_amdgcn_s_setprio(0);
        __builtin_amdgcn_s_barrier();

        // ---------- phase 4: quad(mh1, nh1); stage kt+2 B-nh0 (freed @p3); fence ----------
        if (kt + 2 < 16) stage_half(Bb, lB, 0, 1, kt + 2, tid);
        __builtin_amdgcn_s_barrier();
        __builtin_amdgcn_s_setprio(1);
#pragma unroll
        for (int mfq = 0; mfq < 4; mfq++)
#pragma unroll
            for (int nfq = 0; nfq < 2; nfq++)
#pragma unroll
                for (int ks = 0; ks < 2; ks++)
                    acc[4 + mfq][2 + nfq] = __builtin_amdgcn_mfma_f32_16x16x32_bf16(
                        afr[mfq][ks], bfr[1][nfq][ks], acc[4 + mfq][2 + nfq], 0, 0, 0);
        __builtin_amdgcn_s_setprio(0);
        if (kt + 2 < 16) {
            asm volatile("s_waitcnt vmcnt(4)" ::: "memory");  // retire kt+1's 4 halves
        } else if (kt + 1 < 16) {
            asm volatile("s_waitcnt vmcnt(0)" ::: "memory");  // tail: retire kt15 fully
        }
        __builtin_amdgcn_s_barrier();
    }

    // ---- epilogue: bias + NT store ----
#pragma unroll
    for (int mf = 0; mf < 8; mf++) {
        int grow = row0 + wm * 128 + mf * 16 + lhi * 4;
#pragma unroll
        for (int nf = 0; nf < 4; nf++) {
            int gcol   = col0 + wn * 64 + nf * 16 + llo;
            float bias = bo[gcol];
#pragma unroll
            for (int r = 0; r < 4; r++)
                __builtin_nontemporal_store(acc[mf][nf][r] + bias,
                                            &out[(size_t)(grow + r) * VOCAB + gcol]);
        }
    }
}

// ---------------- host ----------------

extern "C" void kernel_launch(void* const* d_in, const int* in_sizes, int n_in,
                              void* d_out, int out_size, void* d_ws, size_t ws_size,
                              hipStream_t stream) {
    const int*   x     = (const int*)d_in[0];
    const float* state = (const float*)d_in[1];
    const float* W_xr  = (const float*)d_in[2];
    const float* W_hr  = (const float*)d_in[3];
    const float* b_r   = (const float*)d_in[4];
    const float* W_xz  = (const float*)d_in[5];
    const float* W_hz  = (const float*)d_in[6];
    const float* b_z   = (const float*)d_in[7];
    const float* W_xh  = (const float*)d_in[8];
    const float* W_hh  = (const float*)d_in[9];
    const float* b_h   = (const float*)d_in[10];
    const float* W_ho  = (const float*)d_in[11];
    const float* b_o   = (const float*)d_in[12];

    float* out    = (float*)d_out;
    float* hstate = out + (size_t)SEQ * BATCH * VOCAB;

    // ws layout (bytes):
    //   0        : hall  bf16 [128][32][1024]   8,388,608  (= GEMM A matrix)
    //   8388608  : rhall bf16 [128][32][1024]   8,388,608
    //   16777216 : bt    bf16 [32000][1024]    65,536,000
    //   82313216 : wrt   bf16 [1024][1024]      2,097,152
    //   84410368 : wzt   bf16                   2,097,152
    //   86507520 : wht   bf16                   2,097,152
    //   88604672 : hinit bf16 [32][1024]           65,536
    //   88670208 : mbox  u32  [2][64][64]          32,768   total 88,702,976
    char* ws = (char*)d_ws;
    unsigned short* hall  = (unsigned short*)ws;
    unsigned short* rhall = (unsigned short*)(ws + 8388608);
    unsigned short* bt    = (unsigned short*)(ws + 16777216);
    unsigned short* wrt   = (unsigned short*)(ws + 82313216);
    unsigned short* wzt   = (unsigned short*)(ws + 84410368);
    unsigned short* wht   = (unsigned short*)(ws + 86507520);
    unsigned short* hinit = (unsigned short*)(ws + 88604672);
    unsigned int*   mbox  = (unsigned int*)(ws + 88670208);

    hipMemsetAsync(mbox, 0, 32768, stream);
    k_prep<<<896, 256, 0, stream>>>(W_hr, wrt, W_hz, wzt, W_hh, wht, state, hinit);

    k_rnn<<<628, 256, 0, stream>>>(x, state, wrt, wzt, wht, W_xr, b_r, W_xz, b_z, W_xh, b_h,
                                   hinit, hall, rhall, hstate, mbox, W_ho, bt);

    k_gemm8<<<dim3(2000), 512, 0, stream>>>(hall, bt, b_o, out);
}